// Round 2
// baseline (2668.881 us; speedup 1.0000x reference)
//
#include <hip/hip_runtime.h>
#include <hip/hip_bf16.h>

// ModulatedConv (StyleGAN2 conv_transpose2d stride=2, K=3) on gfx950.
// out[b,o,y,x] = inv[b,o] * sum_{i,ky,kx} (scale_w*weight[o,i,ky,kx]) * (s[b,i]*x[b,i,h,w])
// Round 4: px-phase-merged blocks (full output lines -> coalesced 128B writes,
// X staged once for both x-parities), A double-buffered in REGISTERS with a
// full-chunk prefetch distance (no top-of-chunk L2 stall), X double-buffered
// in LDS (one barrier per chunk), ts-grouped B reads (taps sharing a site-slot
// offset reuse one ds_read_b128). o=64 per block keeps acc at 64 VGPR.

typedef __attribute__((ext_vector_type(8))) short short8;
typedef __attribute__((ext_vector_type(4))) float floatx4;

#define CIN   512
#define COUT  512
#define OW    65
#define NSITE 1089     // 33*33 sites (u,v); out y=2u+py, x=2v+px

__device__ __forceinline__ void gload16(const void* g, void* l) {
    __builtin_amdgcn_global_load_lds(
        (const __attribute__((address_space(1))) void*)g,
        (__attribute__((address_space(3))) void*)l, 16, 0, 0);
}

// ---- prep kernels ------------------------------------------------------

// s[b,i] = (1/16) * dot(w[b,:], lin_w[i,:]) + lin_b[i]
__global__ void k_s(const float* __restrict__ w, const float* __restrict__ lin_w,
                    const float* __restrict__ lin_b, float* __restrict__ s)
{
    int i = blockIdx.x * 256 + threadIdx.x;
    int b = blockIdx.y;
    const float* wr = w + b * 512;
    const float* lr = lin_w + (size_t)i * 512;
    float acc = 0.f;
    for (int d = 0; d < 512; d += 4) {
        float4 a = *(const float4*)(wr + d);
        float4 c = *(const float4*)(lr + d);
        acc += a.x*c.x + a.y*c.y + a.z*c.z + a.w*c.w;
    }
    s[b * 512 + i] = acc * 0.0625f + lin_b[i];
}

// fused: q[o,i] = sum_kk weight[o,i,kk]^2 ; wT[t][o][i] = bf16(weight[o,i,t]/48)
__global__ void k_wq(const float* __restrict__ weight,
                     __hip_bfloat16* __restrict__ wT, float* __restrict__ q)
{
    int idx = blockIdx.x * 256 + threadIdx.x;   // o*512+i, < 262144
    const float* p = weight + (size_t)idx * 9;
    float v[9], acc = 0.f;
#pragma unroll
    for (int j = 0; j < 9; ++j) { v[j] = p[j]; acc += v[j] * v[j]; }
    q[idx] = acc;
#pragma unroll
    for (int t = 0; t < 9; ++t)
        wT[t * 262144 + idx] = __float2bfloat16(v[t] * (1.0f / 48.0f));
}

// inv[b,o] = 1/sqrt((1/2304) * sum_i s[b,i]^2 q[o,i] + 1e-8)
__global__ void k_inv(const float* __restrict__ s, const float* __restrict__ q,
                      float* __restrict__ inv)
{
    int idx = blockIdx.x * 256 + threadIdx.x;   // b*512+o
    int b = idx >> 9;
    int o = idx & 511;
    const float* sp = s + b * 512;
    const float* qp = q + (size_t)o * 512;
    float acc = 0.f;
    for (int i = 0; i < 512; i += 4) {
        float4 sv = *(const float4*)(sp + i);
        float4 qv = *(const float4*)(qp + i);
        acc += sv.x*sv.x*qv.x + sv.y*sv.y*qv.y + sv.z*sv.z*qv.z + sv.w*sv.w*qv.w;
    }
    inv[idx] = 1.0f / sqrtf(acc * (1.0f / 2304.0f) + 1e-8f);
}

// zero the halo border of xmp [16][34][34][512]
__global__ void k_zero(__hip_bfloat16* __restrict__ xmp)
{
    int idx = blockIdx.x * 256 + threadIdx.x;   // < 16*132*64
    int kc = idx & 63;
    int j  = (idx >> 6) % 132;
    int b  = (idx >> 6) / 132;
    int r, c;
    if (j < 34)       { r = 0;          c = j; }
    else if (j < 68)  { r = 33;         c = j - 34; }
    else if (j < 100) { r = j - 68 + 1; c = 0; }
    else              { r = j - 100 + 1; c = 33; }
    uint4 z = {0u, 0u, 0u, 0u};
    *(uint4*)(xmp + (((size_t)b * 34 + r) * 34 + c) * 512 + kc * 8) = z;
}

// xmp[b][h+1][w+1][i] = bf16(s[b,i] * x[b,i,h,w])   (channel-minor, padded halo)
__global__ void k_xprep(const float* __restrict__ x, const float* __restrict__ s,
                        __hip_bfloat16* __restrict__ xmp)
{
    __shared__ float tile[32][33];
    int i0 = blockIdx.x * 32;
    int h  = blockIdx.y;
    int b  = blockIdx.z;
    int tw = threadIdx.x & 31;
    int ti = threadIdx.x >> 5;
#pragma unroll
    for (int r = 0; r < 4; ++r) {
        int il = ti + r * 8;
        int i  = i0 + il;
        tile[il][tw] = x[(((size_t)b * 512 + i) * 32 + h) * 32 + tw] * s[b * 512 + i];
    }
    __syncthreads();
#pragma unroll
    for (int r = 0; r < 4; ++r) {
        int wc = ti + r * 8;
        xmp[(((size_t)b * 34 + h + 1) * 34 + (wc + 1)) * 512 + i0 + tw] =
            __float2bfloat16(tile[tw][wc]);
    }
}

// ---- main conv kernel --------------------------------------------------
// Block tile: o=64 x sites=128 x both px parities (py fixed per block).
// 4 waves = 2 wm (o half) x 2 wn (site half); per wave a=2 A-frags, f=4
// B-frags, acc[px][a][f] = 2*2*4 floatx4 = 64 VGPR.
// Taps grouped by shared site-slot offset ts: py0 {ts35:(t0,px0)(t1,px1),
// ts34:(t2,px0), ts1:(t6,px0)(t7,px1), ts0:(t8,px0)}; py1 {ts35:(t3,px0)
// (t4,px1), ts34:(t5,px0)} -> one B read feeds all taps in a group.
// Pipeline per chunk: issue X-stage(kc+1)->LDS[^1] and A-loads(kc+1)->regs
// at top, compute from A(kc) regs + X LDS[cur], single barrier (its vmcnt(0)
// drain lands after ~930 cyc of MFMA -> latency hidden).

template <int PY> struct PT;
template <> struct PT<0> {
    static constexpr int NT = 6, NG = 4;
    static constexpr int TAPL[6] = {0, 1, 2, 6, 7, 8};
    static constexpr int GTS[4]  = {35, 34, 1, 0};
    static constexpr int GSZ[4]  = {2, 1, 2, 1};
    static constexpr int GST[4]  = {0, 2, 3, 5};
    static constexpr int GPX[6]  = {0, 1, 0, 0, 1, 0};
};
template <> struct PT<1> {
    static constexpr int NT = 3, NG = 2;
    static constexpr int TAPL[3] = {3, 4, 5};
    static constexpr int GTS[2]  = {35, 34};
    static constexpr int GSZ[2]  = {2, 1};
    static constexpr int GST[2]  = {0, 2};
    static constexpr int GPX[3]  = {0, 1, 0};
};

template <int PY>
__device__ __forceinline__ void conv_body(
    const __hip_bfloat16* __restrict__ wT,
    const __hip_bfloat16* __restrict__ xmp,
    const float* __restrict__ inv,
    float* __restrict__ out,
    short* Xl, const int site_tile, const int o_tile, const int b)
{
    using T = PT<PY>;
    constexpr int NT = T::NT, NG = T::NG;

    const int tid  = threadIdx.x;
    const int lane = tid & 63;
    const int wv   = tid >> 6;
    const int wm   = wv & 1;
    const int wn   = wv >> 1;
    const int quad = lane >> 4;
    const int c16  = lane & 15;

    const int s0     = site_tile * 128;
    const int u_base = s0 / 33;
    const int o_base = o_tile * 64;

    // A fragment global element offsets (within one tap slice, before k0)
    int aoffg[2];
#pragma unroll
    for (int a = 0; a < 2; ++a)
        aoffg[a] = (wm * 32 + a * 16 + c16) * CIN + quad * 8;

    const __hip_bfloat16* wtapP[NT];
#pragma unroll
    for (int t = 0; t < NT; ++t)
        wtapP[t] = wT + ((size_t)(T::TAPL[t] * COUT + o_base)) * CIN;

    // B fragment LDS offsets per (ts-group, f), swizzled
    int boff[NG][4];
#pragma unroll
    for (int f = 0; f < 4; ++f) {
        int site = s0 + wn * 64 + f * 16 + c16;
        int u = site / 33;
        int v = site - u * 33;
        int sb = (u - u_base) * 34 + v;
#pragma unroll
        for (int g = 0; g < NG; ++g) {
            int sl = sb + T::GTS[g];
            boff[g][f] = sl * 32 + ((quad ^ ((sl >> 1) & 3)) << 3);
        }
    }
    // X staging global pointers (hoisted; add k per chunk)
    const __hip_bfloat16* xg[4];
#pragma unroll
    for (int it = 0; it < 4; ++it) {
        int ch   = it * 256 + tid;
        int slot = ch >> 2;
        int kg   = (ch & 3) ^ ((slot >> 1) & 3);
        int r    = slot / 34;
        int c    = slot - r * 34;
        int h1   = u_base + r;                  // padded xmp row (= h_x + 1)
        xg[it] = (slot < 204 && h1 <= 33)
                   ? xmp + (((size_t)b * 34 + h1) * 34 + c) * 512 + kg * 8
                   : xmp;                       // dummy; those slots never read
    }
    // wave-uniform LDS staging base (shorts)
    const int wub = (tid & 192) * 8;

    floatx4 acc[2][2][4];
#pragma unroll
    for (int p = 0; p < 2; ++p)
#pragma unroll
        for (int a = 0; a < 2; ++a)
#pragma unroll
            for (int f = 0; f < 4; ++f)
                acc[p][a][f] = (floatx4){0.f, 0.f, 0.f, 0.f};

    short8 Aa[NT][2], Ab[NT][2];

    // prologue: stage chunk 0 (X -> buf0, A -> Aa)
#pragma unroll
    for (int it = 0; it < 4; ++it)
        gload16(xg[it], &Xl[it * 2048 + wub]);
#pragma unroll
    for (int t = 0; t < NT; ++t)
#pragma unroll
        for (int a = 0; a < 2; ++a)
            Aa[t][a] = *(const short8*)(wtapP[t] + aoffg[a]);
    __syncthreads();

    auto chunk = [&](short8 (&Ac)[NT][2], short8 (&An)[NT][2], int kc) {
        const int cb = (kc & 1) * 8192;
        const int nb = cb ^ 8192;
        const int k1 = (kc + 1) * 32;
        if (kc < 15) {
#pragma unroll
            for (int it = 0; it < 4; ++it)
                gload16(xg[it] + k1, &Xl[nb + it * 2048 + wub]);
#pragma unroll
            for (int t = 0; t < NT; ++t)
#pragma unroll
                for (int a = 0; a < 2; ++a)
                    An[t][a] = *(const short8*)(wtapP[t] + aoffg[a] + k1);
        }
#pragma unroll
        for (int g = 0; g < NG; ++g) {
            short8 B0 = *(const short8*)(&Xl[cb + boff[g][0]]);
            short8 B1 = *(const short8*)(&Xl[cb + boff[g][1]]);
            short8 B2 = *(const short8*)(&Xl[cb + boff[g][2]]);
            short8 B3 = *(const short8*)(&Xl[cb + boff[g][3]]);
#pragma unroll
            for (int j = 0; j < T::GSZ[g]; ++j) {
                constexpr auto& GST = T::GST;
                const int ti = GST[g] + j;
                const int px = T::GPX[ti];
                acc[px][0][0] = __builtin_amdgcn_mfma_f32_16x16x32_bf16(Ac[ti][0], B0, acc[px][0][0], 0, 0, 0);
                acc[px][1][0] = __builtin_amdgcn_mfma_f32_16x16x32_bf16(Ac[ti][1], B0, acc[px][1][0], 0, 0, 0);
                acc[px][0][1] = __builtin_amdgcn_mfma_f32_16x16x32_bf16(Ac[ti][0], B1, acc[px][0][1], 0, 0, 0);
                acc[px][1][1] = __builtin_amdgcn_mfma_f32_16x16x32_bf16(Ac[ti][1], B1, acc[px][1][1], 0, 0, 0);
                acc[px][0][2] = __builtin_amdgcn_mfma_f32_16x16x32_bf16(Ac[ti][0], B2, acc[px][0][2], 0, 0, 0);
                acc[px][1][2] = __builtin_amdgcn_mfma_f32_16x16x32_bf16(Ac[ti][1], B2, acc[px][1][2], 0, 0, 0);
                acc[px][0][3] = __builtin_amdgcn_mfma_f32_16x16x32_bf16(Ac[ti][0], B3, acc[px][0][3], 0, 0, 0);
                acc[px][1][3] = __builtin_amdgcn_mfma_f32_16x16x32_bf16(Ac[ti][1], B3, acc[px][1][3], 0, 0, 0);
            }
        }
        __syncthreads();
    };

    for (int kc = 0; kc < 16; kc += 2) {
        chunk(Aa, Ab, kc);
        chunk(Ab, Aa, kc + 1);
    }

    // epilogue: D col(lane&15)->site, row(quad*4+reg)->o; both px write the
    // same output line (x = 2v, 2v+1) -> contiguous 128B per (a,f,r) frag row.
#pragma unroll
    for (int a = 0; a < 2; ++a) {
        const int ob = o_base + wm * 32 + a * 16 + quad * 4;
        float iv[4];
#pragma unroll
        for (int r = 0; r < 4; ++r) iv[r] = inv[b * COUT + ob + r];
#pragma unroll
        for (int f = 0; f < 4; ++f) {
            int site = s0 + wn * 64 + f * 16 + c16;
            if (site < NSITE) {
                int u = site / 33;
                int v = site - u * 33;
                int y = 2 * u + PY;
                if (y < OW) {
                    int x0 = 2 * v;
#pragma unroll
                    for (int r = 0; r < 4; ++r) {
                        size_t oi = ((size_t)(b * COUT + ob + r) * OW + y) * OW + x0;
                        out[oi] = acc[0][a][f][r] * iv[r];
                        if (v < 32)
                            out[oi + 1] = acc[1][a][f][r] * iv[r];
                    }
                }
            }
        }
    }
}

__global__ __launch_bounds__(256, 2)
void conv_main(const __hip_bfloat16* __restrict__ wT,
               const __hip_bfloat16* __restrict__ xmp,
               const float* __restrict__ inv,
               float* __restrict__ out)
{
    __shared__ short Xl[16384];   // 32 KB: 2 x (256 slots x 32 k)

    // XCD-chunked swizzle: hw linear id n -> XCD ~ n%8. XCD j gets logical
    // range [j*288,(j+1)*288) = exactly 2 batch slices; within: b outer,
    // o_tile (8), py (2), site (9) inner. Working set per XCD ~ xmp[b]
    // 1.18MB + wT o-slice 0.58MB -> fits 4MB L2.
    const int n  = blockIdx.x + 9 * blockIdx.y + 144 * blockIdx.z;
    const int lg = (n & 7) * 288 + (n >> 3);
    const int b  = lg / 144;
    int rem = lg - b * 144;
    const int o_tile = rem / 18;
    rem -= o_tile * 18;
    const int py   = rem / 9;
    const int site = rem - py * 9;

    if (py == 0) conv_body<0>(wT, xmp, inv, out, Xl, site, o_tile, b);
    else         conv_body<1>(wT, xmp, inv, out, Xl, site, o_tile, b);
}

// ---- launcher ----------------------------------------------------------
extern "C" void kernel_launch(void* const* d_in, const int* in_sizes, int n_in,
                              void* d_out, int out_size, void* d_ws, size_t ws_size,
                              hipStream_t stream)
{
    const float* x      = (const float*)d_in[0];   // (16,512,32,32)
    const float* w      = (const float*)d_in[1];   // (16,512)
    const float* weight = (const float*)d_in[2];   // (1,512,512,3,3)
    const float* lin_w  = (const float*)d_in[3];   // (512,512)
    const float* lin_b  = (const float*)d_in[4];   // (512,)
    float* out = (float*)d_out;                    // (16,512,65,65)

    char* ws = (char*)d_ws;
    float* s_buf   = (float*)(ws);                         //   32 KB
    float* inv_buf = (float*)(ws + 32768);                 //   32 KB
    float* q_buf   = (float*)(ws + 65536);                 //    1 MB
    __hip_bfloat16* wT  = (__hip_bfloat16*)(ws + 1114112); // 4.72 MB [9][512][512]
    __hip_bfloat16* xmp = (__hip_bfloat16*)(ws + 5832704); // 18.9 MB [16][34][34][512]

    k_s    <<<dim3(2, 16),      256, 0, stream>>>(w, lin_w, lin_b, s_buf);
    k_wq   <<<1024,             256, 0, stream>>>(weight, wT, q_buf);
    k_zero <<<528,              256, 0, stream>>>(xmp);
    k_inv  <<<32,               256, 0, stream>>>(s_buf, q_buf, inv_buf);
    k_xprep<<<dim3(16, 32, 16), 256, 0, stream>>>(x, s_buf, xmp);
    conv_main<<<dim3(9, 16, 16), 256, 0, stream>>>(wT, xmp, inv_buf, out);
}

// Round 3
// 403.813 us; speedup vs baseline: 6.6092x; 6.6092x over previous
//
#include <hip/hip_runtime.h>
#include <hip/hip_bf16.h>

// ModulatedConv (StyleGAN2 conv_transpose2d stride=2, K=3) on gfx950.
// out[b,o,y,x] = inv[b,o] * sum_{i,ky,kx} (scale_w*weight[o,i,ky,kx]) * (s[b,i]*x[b,i,h,w])
// Round 5: r2's schedule (px-merged blocks, A double-buffered in registers
// with full-chunk prefetch distance, X double-buffered in LDS, ts-grouped B
// reads) but spill-safe codegen: NO lambda / array-by-reference -- the
// double-buffer swap is macro-expanded with literal buffer indices so SROA
// keeps Ar[][][] in VGPRs (r2's lambda demoted it to scratch: VGPR=104,
// WRITE_SIZE=5GB of spill traffic).

typedef __attribute__((ext_vector_type(8))) short short8;
typedef __attribute__((ext_vector_type(4))) float floatx4;

#define CIN   512
#define COUT  512
#define OW    65
#define NSITE 1089     // 33*33 sites (u,v); out y=2u+py, x=2v+px

__device__ __forceinline__ void gload16(const void* g, void* l) {
    __builtin_amdgcn_global_load_lds(
        (const __attribute__((address_space(1))) void*)g,
        (__attribute__((address_space(3))) void*)l, 16, 0, 0);
}

// ---- prep kernels ------------------------------------------------------

// s[b,i] = (1/16) * dot(w[b,:], lin_w[i,:]) + lin_b[i]
__global__ void k_s(const float* __restrict__ w, const float* __restrict__ lin_w,
                    const float* __restrict__ lin_b, float* __restrict__ s)
{
    int i = blockIdx.x * 256 + threadIdx.x;
    int b = blockIdx.y;
    const float* wr = w + b * 512;
    const float* lr = lin_w + (size_t)i * 512;
    float acc = 0.f;
    for (int d = 0; d < 512; d += 4) {
        float4 a = *(const float4*)(wr + d);
        float4 c = *(const float4*)(lr + d);
        acc += a.x*c.x + a.y*c.y + a.z*c.z + a.w*c.w;
    }
    s[b * 512 + i] = acc * 0.0625f + lin_b[i];
}

// fused: q[o,i] = sum_kk weight[o,i,kk]^2 ; wT[t][o][i] = bf16(weight[o,i,t]/48)
__global__ void k_wq(const float* __restrict__ weight,
                     __hip_bfloat16* __restrict__ wT, float* __restrict__ q)
{
    int idx = blockIdx.x * 256 + threadIdx.x;   // o*512+i, < 262144
    const float* p = weight + (size_t)idx * 9;
    float v[9], acc = 0.f;
#pragma unroll
    for (int j = 0; j < 9; ++j) { v[j] = p[j]; acc += v[j] * v[j]; }
    q[idx] = acc;
#pragma unroll
    for (int t = 0; t < 9; ++t)
        wT[t * 262144 + idx] = __float2bfloat16(v[t] * (1.0f / 48.0f));
}

// inv[b,o] = 1/sqrt((1/2304) * sum_i s[b,i]^2 q[o,i] + 1e-8)
__global__ void k_inv(const float* __restrict__ s, const float* __restrict__ q,
                      float* __restrict__ inv)
{
    int idx = blockIdx.x * 256 + threadIdx.x;   // b*512+o
    int b = idx >> 9;
    int o = idx & 511;
    const float* sp = s + b * 512;
    const float* qp = q + (size_t)o * 512;
    float acc = 0.f;
    for (int i = 0; i < 512; i += 4) {
        float4 sv = *(const float4*)(sp + i);
        float4 qv = *(const float4*)(qp + i);
        acc += sv.x*sv.x*qv.x + sv.y*sv.y*qv.y + sv.z*sv.z*qv.z + sv.w*sv.w*qv.w;
    }
    inv[idx] = 1.0f / sqrtf(acc * (1.0f / 2304.0f) + 1e-8f);
}

// zero the halo border of xmp [16][34][34][512]
__global__ void k_zero(__hip_bfloat16* __restrict__ xmp)
{
    int idx = blockIdx.x * 256 + threadIdx.x;   // < 16*132*64
    int kc = idx & 63;
    int j  = (idx >> 6) % 132;
    int b  = (idx >> 6) / 132;
    int r, c;
    if (j < 34)       { r = 0;          c = j; }
    else if (j < 68)  { r = 33;         c = j - 34; }
    else if (j < 100) { r = j - 68 + 1; c = 0; }
    else              { r = j - 100 + 1; c = 33; }
    uint4 z = {0u, 0u, 0u, 0u};
    *(uint4*)(xmp + (((size_t)b * 34 + r) * 34 + c) * 512 + kc * 8) = z;
}

// xmp[b][h+1][w+1][i] = bf16(s[b,i] * x[b,i,h,w])   (channel-minor, padded halo)
__global__ void k_xprep(const float* __restrict__ x, const float* __restrict__ s,
                        __hip_bfloat16* __restrict__ xmp)
{
    __shared__ float tile[32][33];
    int i0 = blockIdx.x * 32;
    int h  = blockIdx.y;
    int b  = blockIdx.z;
    int tw = threadIdx.x & 31;
    int ti = threadIdx.x >> 5;
#pragma unroll
    for (int r = 0; r < 4; ++r) {
        int il = ti + r * 8;
        int i  = i0 + il;
        tile[il][tw] = x[(((size_t)b * 512 + i) * 32 + h) * 32 + tw] * s[b * 512 + i];
    }
    __syncthreads();
#pragma unroll
    for (int r = 0; r < 4; ++r) {
        int wc = ti + r * 8;
        xmp[(((size_t)b * 34 + h + 1) * 34 + (wc + 1)) * 512 + i0 + tw] =
            __float2bfloat16(tile[tw][wc]);
    }
}

// ---- main conv kernel --------------------------------------------------
// Block tile: o=64 x sites=128 x both px parities (py fixed per block).
// 4 waves = 2 wm (o half) x 2 wn (site half); per wave a=2 A-frags, f=4
// B-frags, acc[px][a][f] = 16 floatx4 = 64 VGPR. A dbuf Ar[2][NT][2] = 96
// VGPR (py0). Pipeline per chunk: issue X-stage(kc+1)->LDS[^buf] and
// A-loads(kc+1)->regs at top, compute chunk kc from regs+LDS, one barrier
// (its vmcnt(0) drain lands after ~900cy of MFMA+ds_read -> hidden).

template <int PY> struct PT;
template <> struct PT<0> {
    static constexpr int NT = 6, NG = 4;
    static constexpr int TAPL[6] = {0, 1, 2, 6, 7, 8};
    static constexpr int GTS[4]  = {35, 34, 1, 0};
    static constexpr int GSZ[4]  = {2, 1, 2, 1};
    static constexpr int GST[4]  = {0, 2, 3, 5};
    static constexpr int GPX[6]  = {0, 1, 0, 0, 1, 0};
};
template <> struct PT<1> {
    static constexpr int NT = 3, NG = 2;
    static constexpr int TAPL[3] = {3, 4, 5};
    static constexpr int GTS[2]  = {35, 34};
    static constexpr int GSZ[2]  = {2, 1};
    static constexpr int GST[2]  = {0, 2};
    static constexpr int GPX[3]  = {0, 1, 0};
};

// Macro-expanded pipeline pieces: all array indices are literals or fully
// unrolled induction vars -> SROA keeps everything in VGPRs.
#define STAGE_X(NB, K1)                                                    \
    { _Pragma("unroll")                                                    \
      for (int it = 0; it < 4; ++it)                                       \
          gload16(xg[it] + (K1), &Xl[(NB) + it * 2048 + wub]); }

#define PREFETCH_A(DST, K1)                                                \
    { _Pragma("unroll")                                                    \
      for (int t = 0; t < NT; ++t) {                                       \
          Ar[DST][t][0] = *(const short8*)(wtapP[t] + aoffg[0] + (K1));    \
          Ar[DST][t][1] = *(const short8*)(wtapP[t] + aoffg[1] + (K1));    \
      } }

#define COMPUTE_GROUPS(CUR, CB)                                            \
    { _Pragma("unroll")                                                    \
      for (int g = 0; g < NG; ++g) {                                       \
          short8 B0 = *(const short8*)(&Xl[(CB) + boff[g][0]]);            \
          short8 B1 = *(const short8*)(&Xl[(CB) + boff[g][1]]);            \
          short8 B2 = *(const short8*)(&Xl[(CB) + boff[g][2]]);            \
          short8 B3 = *(const short8*)(&Xl[(CB) + boff[g][3]]);            \
          _Pragma("unroll")                                                \
          for (int j = 0; j < T::GSZ[g]; ++j) {                            \
              const int ti = T::GST[g] + j;                                \
              const int px = T::GPX[ti];                                   \
              acc[px][0][0] = __builtin_amdgcn_mfma_f32_16x16x32_bf16(Ar[CUR][ti][0], B0, acc[px][0][0], 0, 0, 0); \
              acc[px][1][0] = __builtin_amdgcn_mfma_f32_16x16x32_bf16(Ar[CUR][ti][1], B0, acc[px][1][0], 0, 0, 0); \
              acc[px][0][1] = __builtin_amdgcn_mfma_f32_16x16x32_bf16(Ar[CUR][ti][0], B1, acc[px][0][1], 0, 0, 0); \
              acc[px][1][1] = __builtin_amdgcn_mfma_f32_16x16x32_bf16(Ar[CUR][ti][1], B1, acc[px][1][1], 0, 0, 0); \
              acc[px][0][2] = __builtin_amdgcn_mfma_f32_16x16x32_bf16(Ar[CUR][ti][0], B2, acc[px][0][2], 0, 0, 0); \
              acc[px][1][2] = __builtin_amdgcn_mfma_f32_16x16x32_bf16(Ar[CUR][ti][1], B2, acc[px][1][2], 0, 0, 0); \
              acc[px][0][3] = __builtin_amdgcn_mfma_f32_16x16x32_bf16(Ar[CUR][ti][0], B3, acc[px][0][3], 0, 0, 0); \
              acc[px][1][3] = __builtin_amdgcn_mfma_f32_16x16x32_bf16(Ar[CUR][ti][1], B3, acc[px][1][3], 0, 0, 0); \
          }                                                                \
      } }

template <int PY>
__device__ __forceinline__ void conv_body(
    const __hip_bfloat16* __restrict__ wT,
    const __hip_bfloat16* __restrict__ xmp,
    const float* __restrict__ inv,
    float* __restrict__ out,
    short* Xl, const int site_tile, const int o_tile, const int b)
{
    using T = PT<PY>;
    constexpr int NT = T::NT, NG = T::NG;

    const int tid  = threadIdx.x;
    const int lane = tid & 63;
    const int wv   = tid >> 6;
    const int wm   = wv & 1;
    const int wn   = wv >> 1;
    const int quad = lane >> 4;
    const int c16  = lane & 15;

    const int s0     = site_tile * 128;
    const int u_base = s0 / 33;
    const int o_base = o_tile * 64;

    // A fragment global element offsets (within one tap slice, before k0)
    int aoffg[2];
#pragma unroll
    for (int a = 0; a < 2; ++a)
        aoffg[a] = (wm * 32 + a * 16 + c16) * CIN + quad * 8;

    const __hip_bfloat16* wtapP[NT];
#pragma unroll
    for (int t = 0; t < NT; ++t)
        wtapP[t] = wT + ((size_t)(T::TAPL[t] * COUT + o_base)) * CIN;

    // B fragment LDS offsets per (ts-group, f), swizzled
    int boff[NG][4];
#pragma unroll
    for (int f = 0; f < 4; ++f) {
        int site = s0 + wn * 64 + f * 16 + c16;
        int u = site / 33;
        int v = site - u * 33;
        int sb = (u - u_base) * 34 + v;
#pragma unroll
        for (int g = 0; g < NG; ++g) {
            int sl = sb + T::GTS[g];
            boff[g][f] = sl * 32 + ((quad ^ ((sl >> 1) & 3)) << 3);
        }
    }
    // X staging global pointers (hoisted; add k per chunk)
    const __hip_bfloat16* xg[4];
#pragma unroll
    for (int it = 0; it < 4; ++it) {
        int ch   = it * 256 + tid;
        int slot = ch >> 2;
        int kg   = (ch & 3) ^ ((slot >> 1) & 3);
        int r    = slot / 34;
        int c    = slot - r * 34;
        int h1   = u_base + r;                  // padded xmp row (= h_x + 1)
        xg[it] = (slot < 204 && h1 <= 33)
                   ? xmp + (((size_t)b * 34 + h1) * 34 + c) * 512 + kg * 8
                   : xmp;                       // dummy; those slots never read
    }
    // wave-uniform LDS staging base (shorts)
    const int wub = (tid & 192) * 8;

    floatx4 acc[2][2][4];
#pragma unroll
    for (int p = 0; p < 2; ++p)
#pragma unroll
        for (int a = 0; a < 2; ++a)
#pragma unroll
            for (int f = 0; f < 4; ++f)
                acc[p][a][f] = (floatx4){0.f, 0.f, 0.f, 0.f};

    short8 Ar[2][NT][2];

    // prologue: stage chunk 0 (X -> buf0, A -> Ar[0])
    STAGE_X(0, 0)
    PREFETCH_A(0, 0)
    __syncthreads();

#pragma unroll 1
    for (int kc = 0; kc < 16; kc += 2) {
        const int k1 = (kc + 1) * 32;
        STAGE_X(8192, k1)
        PREFETCH_A(1, k1)
        COMPUTE_GROUPS(0, 0)
        __syncthreads();

        const int k2 = (kc + 2) * 32;
        if (kc < 14) {
            STAGE_X(0, k2)
            PREFETCH_A(0, k2)
        }
        COMPUTE_GROUPS(1, 8192)
        __syncthreads();
    }

    // epilogue: D col(lane&15)->site, row(quad*4+reg)->o; both px write the
    // same output line (x = 2v, 2v+1) -> contiguous 128B per (a,f,r) frag row.
#pragma unroll
    for (int a = 0; a < 2; ++a) {
        const int ob = o_base + wm * 32 + a * 16 + quad * 4;
        float iv[4];
#pragma unroll
        for (int r = 0; r < 4; ++r) iv[r] = inv[b * COUT + ob + r];
#pragma unroll
        for (int f = 0; f < 4; ++f) {
            int site = s0 + wn * 64 + f * 16 + c16;
            if (site < NSITE) {
                int u = site / 33;
                int v = site - u * 33;
                int y = 2 * u + PY;
                if (y < OW) {
                    int x0 = 2 * v;
#pragma unroll
                    for (int r = 0; r < 4; ++r) {
                        size_t oi = ((size_t)(b * COUT + ob + r) * OW + y) * OW + x0;
                        out[oi] = acc[0][a][f][r] * iv[r];
                        if (v < 32)
                            out[oi + 1] = acc[1][a][f][r] * iv[r];
                    }
                }
            }
        }
    }
}

__global__ __launch_bounds__(256, 2)
void conv_main(const __hip_bfloat16* __restrict__ wT,
               const __hip_bfloat16* __restrict__ xmp,
               const float* __restrict__ inv,
               float* __restrict__ out)
{
    __shared__ short Xl[16384];   // 32 KB: 2 x (256 slots x 32 k)

    // XCD-chunked swizzle: hw linear id n -> XCD ~ n%8. XCD j gets logical
    // range [j*288,(j+1)*288) = exactly 2 batch slices; within: b outer,
    // o_tile (8), py (2), site (9) inner. Working set per XCD ~ xmp[b]
    // 1.18MB + wT o-slice 0.58MB -> fits 4MB L2.
    const int n  = blockIdx.x + 9 * blockIdx.y + 144 * blockIdx.z;
    const int lg = (n & 7) * 288 + (n >> 3);
    const int b  = lg / 144;
    int rem = lg - b * 144;
    const int o_tile = rem / 18;
    rem -= o_tile * 18;
    const int py   = rem / 9;
    const int site = rem - py * 9;

    if (py == 0) conv_body<0>(wT, xmp, inv, out, Xl, site, o_tile, b);
    else         conv_body<1>(wT, xmp, inv, out, Xl, site, o_tile, b);
}

// ---- launcher ----------------------------------------------------------
extern "C" void kernel_launch(void* const* d_in, const int* in_sizes, int n_in,
                              void* d_out, int out_size, void* d_ws, size_t ws_size,
                              hipStream_t stream)
{
    const float* x      = (const float*)d_in[0];   // (16,512,32,32)
    const float* w      = (const float*)d_in[1];   // (16,512)
    const float* weight = (const float*)d_in[2];   // (1,512,512,3,3)
    const float* lin_w  = (const float*)d_in[3];   // (512,512)
    const float* lin_b  = (const float*)d_in[4];   // (512,)
    float* out = (float*)d_out;                    // (16,512,65,65)

    char* ws = (char*)d_ws;
    float* s_buf   = (float*)(ws);                         //   32 KB
    float* inv_buf = (float*)(ws + 32768);                 //   32 KB
    float* q_buf   = (float*)(ws + 65536);                 //    1 MB
    __hip_bfloat16* wT  = (__hip_bfloat16*)(ws + 1114112); // 4.72 MB [9][512][512]
    __hip_bfloat16* xmp = (__hip_bfloat16*)(ws + 5832704); // 18.9 MB [16][34][34][512]

    k_s    <<<dim3(2, 16),      256, 0, stream>>>(w, lin_w, lin_b, s_buf);
    k_wq   <<<1024,             256, 0, stream>>>(weight, wT, q_buf);
    k_zero <<<528,              256, 0, stream>>>(xmp);
    k_inv  <<<32,               256, 0, stream>>>(s_buf, q_buf, inv_buf);
    k_xprep<<<dim3(16, 32, 16), 256, 0, stream>>>(x, s_buf, xmp);
    conv_main<<<dim3(9, 16, 16), 256, 0, stream>>>(wT, xmp, inv_buf, out);
}